// Round 5
// baseline (326.393 us; speedup 1.0000x reference)
//
#include <hip/hip_runtime.h>

#define D 64          // node/edge feature dim
#define HID 128       // hidden dim
#define MLPB 1024     // MLP block size (16 waves)
#define WPB 16        // waves per MLP block
#define NB 8          // nodes per wave-batch
#define WIN_SHIFT 13  // 8192 nodes per place-window -> ~1MB elist window (L2-resident)

typedef unsigned short ush;

// bf16 round-to-nearest-even (values are finite normals; no NaN handling)
__device__ __forceinline__ ush f2bf(float f)
{
    unsigned u = __float_as_uint(f);
    return (ush)((u + 0x7FFF + ((u >> 16) & 1)) >> 16);
}
__device__ __forceinline__ float bf_lo(unsigned p) { return __uint_as_float(p << 16); }
__device__ __forceinline__ float bf_hi(unsigned p) { return __uint_as_float(p & 0xFFFF0000u); }

// ---------------------------------------------------------------------------
// Index dtype: reference says int64, harness may deliver int32. Probe high
// words of the first 64 pairs: int64 -> all zero (ids < 50000); int32 ->
// random node ids, P(all zero) ~ (2e-5)^64 ~ 0. Deterministic.
// ---------------------------------------------------------------------------
__device__ __forceinline__ bool detect_i64(const int* __restrict__ eidx, int lane)
{
    int probe = eidx[2 * lane + 1];
    return (__ballot(probe == 0) == ~0ULL);
}

// ---------- CSR build + bf16 conversion ------------------------------------
// Entry t in [0, 2E): t < E -> src of edge t; t >= E -> dst of edge t-E.
// Also (tier C) streams x_edge once, writing a bf16 copy (102.4MB, L3-fits).
__global__ __launch_bounds__(256)
void csr_hist_conv(const int* __restrict__ eidx, int* __restrict__ counts,
                   int* __restrict__ nid, int write_nid,
                   const float* __restrict__ x_edge, ush* __restrict__ xbf,
                   int do_conv, int n_edges)
{
    const int t = blockIdx.x * 256 + threadIdx.x;
    const int E2 = 2 * n_edges;
    bool is64 = detect_i64(eidx, threadIdx.x & 63);
    if (t < E2) {
        int idx = is64 ? eidx[2 * (size_t)t] : eidx[t];
        if (write_nid) nid[t] = idx;
        atomicAdd(&counts[idx], 1);
    }
    if (do_conv) {
        const int nf4 = n_edges * 16;            // 12.8M float4s
        const int total = gridDim.x * 256;
        const float4* __restrict__ xe4 = (const float4*)x_edge;
        ushort4* __restrict__ xb4 = (ushort4*)xbf;
        for (int c = t; c < nf4; c += total) {
            float4 v = xe4[c];
            xb4[c] = make_ushort4(f2bf(v.x), f2bf(v.y), f2bf(v.z), f2bf(v.w));
        }
    }
}

__global__ __launch_bounds__(256)
void csr_blocksum(const int* __restrict__ counts, int* __restrict__ bsum, int n)
{
    int i = blockIdx.x * 256 + threadIdx.x;
    int v = (i < n) ? counts[i] : 0;
    #pragma unroll
    for (int o = 1; o < 64; o <<= 1) v += __shfl_xor(v, o);
    __shared__ int ws[4];
    if ((threadIdx.x & 63) == 0) ws[threadIdx.x >> 6] = v;
    __syncthreads();
    if (threadIdx.x == 0) bsum[blockIdx.x] = ws[0] + ws[1] + ws[2] + ws[3];
}

__global__ __launch_bounds__(256)
void csr_scan_bsum(int* __restrict__ bsum, int nb)
{
    __shared__ int s[256];
    int i = threadIdx.x;
    int v = (i < nb) ? bsum[i] : 0;
    s[i] = v; __syncthreads();
    #pragma unroll
    for (int o = 1; o < 256; o <<= 1) {
        int t = (i >= o) ? s[i - o] : 0;
        __syncthreads();
        s[i] += t;
        __syncthreads();
    }
    if (i < nb) bsum[i] = s[i] - v;   // exclusive
}

__global__ __launch_bounds__(256)
void csr_scan_final(const int* __restrict__ counts, const int* __restrict__ bsum,
                    int* __restrict__ offsets, int* __restrict__ cursor, int n)
{
    __shared__ int s[256];
    int i = blockIdx.x * 256 + threadIdx.x;
    int v = (i < n) ? counts[i] : 0;
    s[threadIdx.x] = v; __syncthreads();
    #pragma unroll
    for (int o = 1; o < 256; o <<= 1) {
        int t = (threadIdx.x >= o) ? s[threadIdx.x - o] : 0;
        __syncthreads();
        s[threadIdx.x] += t;
        __syncthreads();
    }
    int excl = s[threadIdx.x] - v + bsum[blockIdx.x];
    if (i < n) { offsets[i] = excl; cursor[i] = excl; }
    if (i == n - 1) offsets[n] = excl + v;   // total = 2E
}

// Windowed place: blockIdx.y = 8192-node window; the window's elist range
// (~1MB) stays cache-resident so random 4B writes coalesce before flushing.
__global__ __launch_bounds__(256)
void csr_place_win(const int* __restrict__ eidx, const int* __restrict__ nid,
                   int use_nid, int* __restrict__ cursor,
                   int* __restrict__ elist, int n_edges)
{
    const int lo = blockIdx.y << WIN_SHIFT;
    const int hi = lo + (1 << WIN_SHIFT);
    const int E2 = 2 * n_edges;
    bool is64 = use_nid ? false : detect_i64(eidx, threadIdx.x & 63);
    const int stride = gridDim.x * 256;
    for (int t = blockIdx.x * 256 + threadIdx.x; t < E2; t += stride) {
        int idx = use_nid ? nid[t] : (is64 ? eidx[2 * (size_t)t] : eidx[t]);
        if (idx >= lo && idx < hi) {
            int eid = (t < n_edges) ? t : t - n_edges;
            int p = atomicAdd(&cursor[idx], 1);
            elist[p] = eid;
        }
    }
}

// ---------- bf16 gather: agg[n] = sum over incident edges of xbf[e] --------
// One wave per node. 8 lanes x uint4(8 bf16) cover one 128B row; 8 row slots,
// 4x unrolled -> 32 edges in flight per wave. f32 accumulation. No LDS.
__global__ __launch_bounds__(256)
void csr_gather_bf16(const ush* __restrict__ xbf, const int* __restrict__ offsets,
                     const int* __restrict__ elist, float* __restrict__ agg,
                     int n_nodes)
{
    const int w = (blockIdx.x * 256 + threadIdx.x) >> 6;
    if (w >= n_nodes) return;
    const int lane = threadIdx.x & 63;
    const int sub = lane >> 3;       // row slot 0..7
    const int q   = lane & 7;        // uint4 index within 128B row
    const uint4* __restrict__ x4 = (const uint4*)xbf;

    const int beg = offsets[w], end = offsets[w + 1];
    float acc[8] = {0.f, 0.f, 0.f, 0.f, 0.f, 0.f, 0.f, 0.f};

    #define ACC8(u) do {                                   \
        acc[0] += bf_lo((u).x); acc[1] += bf_hi((u).x);    \
        acc[2] += bf_lo((u).y); acc[3] += bf_hi((u).y);    \
        acc[4] += bf_lo((u).z); acc[5] += bf_hi((u).z);    \
        acc[6] += bf_lo((u).w); acc[7] += bf_hi((u).w);    \
    } while (0)

    int i = beg + sub;
    for (; i + 24 < end; i += 32) {
        int e0 = elist[i];
        int e1 = elist[i + 8];
        int e2 = elist[i + 16];
        int e3 = elist[i + 24];
        uint4 u0 = x4[(size_t)e0 * 8 + q];
        uint4 u1 = x4[(size_t)e1 * 8 + q];
        uint4 u2 = x4[(size_t)e2 * 8 + q];
        uint4 u3 = x4[(size_t)e3 * 8 + q];
        ACC8(u0); ACC8(u1); ACC8(u2); ACC8(u3);
    }
    for (; i < end; i += 8) {
        uint4 u = x4[(size_t)elist[i] * 8 + q];
        ACC8(u);
    }
    #undef ACC8

    // reduce across the 8 row slots (lane bits 3,4,5)
    #pragma unroll
    for (int m = 8; m < 64; m <<= 1) {
        #pragma unroll
        for (int r = 0; r < 8; ++r) acc[r] += __shfl_xor(acc[r], m);
    }
    if (sub == 0) {
        float4* ap = (float4*)(agg + (size_t)w * D + q * 8);
        ap[0] = make_float4(acc[0], acc[1], acc[2], acc[3]);
        ap[1] = make_float4(acc[4], acc[5], acc[6], acc[7]);
    }
}

// ---------- f32 gather (tier A/B fallback) ---------------------------------
__global__ __launch_bounds__(256)
void csr_gather4(const float* __restrict__ x_edge, const int* __restrict__ offsets,
                 const int* __restrict__ elist, float* __restrict__ agg, int n_nodes)
{
    const int w = (blockIdx.x * 256 + threadIdx.x) >> 6;
    if (w >= n_nodes) return;
    const int lane = threadIdx.x & 63;
    const int sub = lane >> 4;
    const int q   = lane & 15;
    const float4* __restrict__ xe4 = (const float4*)x_edge;

    const int beg = offsets[w], end = offsets[w + 1];
    float4 acc = make_float4(0.f, 0.f, 0.f, 0.f);

    int i = beg + sub;
    for (; i + 12 < end; i += 16) {
        int e0 = elist[i];
        int e1 = elist[i + 4];
        int e2 = elist[i + 8];
        int e3 = elist[i + 12];
        float4 v0 = xe4[(size_t)e0 * 16 + q];
        float4 v1 = xe4[(size_t)e1 * 16 + q];
        float4 v2 = xe4[(size_t)e2 * 16 + q];
        float4 v3 = xe4[(size_t)e3 * 16 + q];
        acc.x += (v0.x + v1.x) + (v2.x + v3.x);
        acc.y += (v0.y + v1.y) + (v2.y + v3.y);
        acc.z += (v0.z + v1.z) + (v2.z + v3.z);
        acc.w += (v0.w + v1.w) + (v2.w + v3.w);
    }
    for (; i < end; i += 4) {
        float4 v = xe4[(size_t)elist[i] * 16 + q];
        acc.x += v.x; acc.y += v.y; acc.z += v.z; acc.w += v.w;
    }
    #pragma unroll
    for (int m = 16; m < 64; m <<= 1) {
        acc.x += __shfl_xor(acc.x, m);
        acc.y += __shfl_xor(acc.y, m);
        acc.z += __shfl_xor(acc.z, m);
        acc.w += __shfl_xor(acc.w, m);
    }
    if (sub == 0)
        ((float4*)agg)[(size_t)w * 16 + q] = acc;
}

// ---------- fallback atomic scatter (tiny ws) ------------------------------
__global__ __launch_bounds__(256)
void nb_scatter(const float* __restrict__ x_edge, const int* __restrict__ eidx,
                float* __restrict__ agg, int n_edges)
{
    long long t = (long long)blockIdx.x * 256 + threadIdx.x;
    int e = (int)(t >> 6);
    if (e >= n_edges) return;
    int d = (int)(t & 63);
    bool is64 = detect_i64(eidx, threadIdx.x & 63);
    int s, dd;
    if (is64) {
        s  = eidx[2 * (size_t)e];
        dd = eidx[2 * ((size_t)n_edges + (size_t)e)];
    } else {
        s  = eidx[e];
        dd = eidx[n_edges + e];
    }
    float v = x_edge[(size_t)e * D + d];
    unsafeAtomicAdd(&agg[(size_t)s * D + d], v);
    unsafeAtomicAdd(&agg[(size_t)dd * D + d], v);
}

// ---------------------------------------------------------------------------
// MLP: out[n] = relu(concat(x_node[n], agg[n]) @ W1 + b1) @ W2 + b2
// NB=8 nodes per wave-batch. W1 staged as float2{W1[k][j],W1[k][j+64]} (one
// b64 feeds 16 FMAs); W2 staged bf16-packed {W2[2q][j],W2[2q+1][j]} (one b32
// feeds 32 FMAs). s_buf holds inputs then hidden (overlaid), 2 float4/entry.
// LDS 146.75KB -> 1 block/CU, 16 waves. agg read from d_out, out in place.
// ---------------------------------------------------------------------------
__global__ __launch_bounds__(MLPB, 1)
void nb_mlp(const float* __restrict__ x_node, const float* __restrict__ agg,
            const float* __restrict__ W1, const float* __restrict__ b1,
            const float* __restrict__ W2, const float* __restrict__ b2,
            float* __restrict__ out, int n_nodes)
{
    __shared__ float2   sW1p[HID * 64];        // 64 KB
    __shared__ unsigned sW2p[64 * 64];         // 16 KB
    __shared__ float    sb1[HID];
    __shared__ float    sb2[D];
    __shared__ float4   s_buf[WPB][128][2];    // 64 KB

    {
        // W1 pairs: sW1p[k*64+j] = (W1[k*128+j], W1[k*128+64+j])
        for (int t = threadIdx.x; t < HID * 64; t += MLPB) {
            int k = t >> 6, j = t & 63;
            sW1p[t] = make_float2(W1[k * HID + j], W1[k * HID + 64 + j]);
        }
        // W2 bf16 pairs: sW2p[q*64+j] = pack(W2[2q][j], W2[2q+1][j])
        for (int t = threadIdx.x; t < 64 * 64; t += MLPB) {
            int q = t >> 6, j = t & 63;
            unsigned lo = f2bf(W2[(2 * q) * D + j]);
            unsigned hi = f2bf(W2[(2 * q + 1) * D + j]);
            sW2p[t] = lo | (hi << 16);
        }
        if (threadIdx.x < 128) sb1[threadIdx.x] = b1[threadIdx.x];
        else if (threadIdx.x < 192) sb2[threadIdx.x - 128] = b2[threadIdx.x - 128];
    }
    __syncthreads();

    const int wave = threadIdx.x >> 6;
    const int lane = threadIdx.x & 63;
    const int group = blockIdx.x * WPB + wave;
    const int ngroups = gridDim.x * WPB;
    const int nbatches = (n_nodes + NB - 1) / NB;

    const float bh0 = sb1[lane], bh1 = sb1[64 + lane];
    const float bo  = sb2[lane];

    for (int g = group; g < nbatches; g += ngroups) {
        const int n0 = g * NB;

        // ---- stage inputs: lane j provides k=j (x_node) and k=64+j (agg) ----
        float vx[NB], va[NB];
        #pragma unroll
        for (int b = 0; b < NB; ++b) {
            const int n = n0 + b;
            const bool ok = (n < n_nodes);
            vx[b] = ok ? x_node[(size_t)n * D + lane] : 0.f;
            va[b] = ok ? agg[(size_t)n * D + lane] : 0.f;
        }
        s_buf[wave][lane][0]      = make_float4(vx[0], vx[1], vx[2], vx[3]);
        s_buf[wave][lane][1]      = make_float4(vx[4], vx[5], vx[6], vx[7]);
        s_buf[wave][64 + lane][0] = make_float4(va[0], va[1], va[2], va[3]);
        s_buf[wave][64 + lane][1] = make_float4(va[4], va[5], va[6], va[7]);
        __builtin_amdgcn_wave_barrier();

        // ---- hidden layer: lane j -> units j and j+64, for 8 nodes ----
        float a0[NB], a1[NB];
        #pragma unroll
        for (int b = 0; b < NB; ++b) { a0[b] = bh0; a1[b] = bh1; }

        #pragma unroll 2
        for (int k = 0; k < 128; ++k) {
            const float4 A0 = s_buf[wave][k][0];     // nodes 0-3 (broadcast)
            const float4 A1 = s_buf[wave][k][1];     // nodes 4-7
            const float2 w  = sW1p[k * 64 + lane];
            a0[0] = fmaf(A0.x, w.x, a0[0]); a1[0] = fmaf(A0.x, w.y, a1[0]);
            a0[1] = fmaf(A0.y, w.x, a0[1]); a1[1] = fmaf(A0.y, w.y, a1[1]);
            a0[2] = fmaf(A0.z, w.x, a0[2]); a1[2] = fmaf(A0.z, w.y, a1[2]);
            a0[3] = fmaf(A0.w, w.x, a0[3]); a1[3] = fmaf(A0.w, w.y, a1[3]);
            a0[4] = fmaf(A1.x, w.x, a0[4]); a1[4] = fmaf(A1.x, w.y, a1[4]);
            a0[5] = fmaf(A1.y, w.x, a0[5]); a1[5] = fmaf(A1.y, w.y, a1[5]);
            a0[6] = fmaf(A1.z, w.x, a0[6]); a1[6] = fmaf(A1.z, w.y, a1[6]);
            a0[7] = fmaf(A1.w, w.x, a0[7]); a1[7] = fmaf(A1.w, w.y, a1[7]);
        }
        __builtin_amdgcn_wave_barrier();   // all s_buf reads done before overlay
        s_buf[wave][lane][0] = make_float4(fmaxf(a0[0], 0.f), fmaxf(a0[1], 0.f),
                                           fmaxf(a0[2], 0.f), fmaxf(a0[3], 0.f));
        s_buf[wave][lane][1] = make_float4(fmaxf(a0[4], 0.f), fmaxf(a0[5], 0.f),
                                           fmaxf(a0[6], 0.f), fmaxf(a0[7], 0.f));
        s_buf[wave][64 + lane][0] = make_float4(fmaxf(a1[0], 0.f), fmaxf(a1[1], 0.f),
                                                fmaxf(a1[2], 0.f), fmaxf(a1[3], 0.f));
        s_buf[wave][64 + lane][1] = make_float4(fmaxf(a1[4], 0.f), fmaxf(a1[5], 0.f),
                                                fmaxf(a1[6], 0.f), fmaxf(a1[7], 0.f));
        __builtin_amdgcn_wave_barrier();

        // ---- output layer: lane j -> out[j] for 8 nodes ----
        float o[NB];
        #pragma unroll
        for (int b = 0; b < NB; ++b) o[b] = bo;
        #pragma unroll 2
        for (int q2 = 0; q2 < 64; ++q2) {
            const unsigned wp = sW2p[q2 * 64 + lane];
            const float w0 = bf_lo(wp), w1 = bf_hi(wp);
            const float4 H0a = s_buf[wave][2 * q2][0];
            const float4 H0b = s_buf[wave][2 * q2][1];
            const float4 H1a = s_buf[wave][2 * q2 + 1][0];
            const float4 H1b = s_buf[wave][2 * q2 + 1][1];
            o[0] = fmaf(H0a.x, w0, o[0]); o[0] = fmaf(H1a.x, w1, o[0]);
            o[1] = fmaf(H0a.y, w0, o[1]); o[1] = fmaf(H1a.y, w1, o[1]);
            o[2] = fmaf(H0a.z, w0, o[2]); o[2] = fmaf(H1a.z, w1, o[2]);
            o[3] = fmaf(H0a.w, w0, o[3]); o[3] = fmaf(H1a.w, w1, o[3]);
            o[4] = fmaf(H0b.x, w0, o[4]); o[4] = fmaf(H1b.x, w1, o[4]);
            o[5] = fmaf(H0b.y, w0, o[5]); o[5] = fmaf(H1b.y, w1, o[5]);
            o[6] = fmaf(H0b.z, w0, o[6]); o[6] = fmaf(H1b.z, w1, o[6]);
            o[7] = fmaf(H0b.w, w0, o[7]); o[7] = fmaf(H1b.w, w1, o[7]);
        }
        #pragma unroll
        for (int b = 0; b < NB; ++b) {
            const int n = n0 + b;
            if (n < n_nodes) out[(size_t)n * D + lane] = o[b];
        }
    }
}

// ---------------------------------------------------------------------------
extern "C" void kernel_launch(void* const* d_in, const int* in_sizes, int n_in,
                              void* d_out, int out_size, void* d_ws, size_t ws_size,
                              hipStream_t stream)
{
    const float* x_node = (const float*)d_in[0];
    const float* x_edge = (const float*)d_in[1];
    const int*   eidx   = (const int*)d_in[2];
    const float* W1     = (const float*)d_in[3];
    const float* b1     = (const float*)d_in[4];
    const float* W2     = (const float*)d_in[5];
    const float* b2     = (const float*)d_in[6];
    float* out = (float*)d_out;

    const int n_nodes = in_sizes[0] / D;     // 50000
    const int n_edges = in_sizes[2] / 2;     // 800000
    const int E2 = 2 * n_edges;

    float* agg = out;   // agg lives in d_out; MLP rewrites rows in place

    // ws words: offsets[N+1] | counts[N] | cursor[N] | bsum[256] | elist[2E]
    //           | nid[2E] | (align 32B) xbf[E*64 ush]
    const size_t wB = (size_t)(n_nodes + 1) + n_nodes + n_nodes + 256 + E2;
    const size_t wA = wB + E2;
    const size_t wA_pad = (wA + 7) & ~(size_t)7;             // 32B align for xbf
    const size_t wC = wA_pad + (size_t)n_edges * 32;         // xbf = E*64 ush = E*32 words
    const size_t needB = wB * 4, needA = wA * 4, needC = wC * 4;

    if (ws_size >= needB) {
        const int tierC = (ws_size >= needC) ? 1 : 0;
        const int use_nid = (tierC || ws_size >= needA) ? 1 : 0;
        int* offsets = (int*)d_ws;
        int* counts  = offsets + (n_nodes + 1);
        int* cursor  = counts + n_nodes;
        int* bsum    = cursor + n_nodes;
        int* elist   = bsum + 256;
        int* nid     = elist + E2;                  // valid if use_nid
        ush* xbf     = (ush*)((int*)d_ws + wA_pad); // valid if tierC

        const int nscan = (n_nodes + 255) / 256;

        hipMemsetAsync(counts, 0, (size_t)n_nodes * 4, stream);
        csr_hist_conv<<<(E2 + 255) / 256, 256, 0, stream>>>(
            eidx, counts, nid, use_nid, x_edge, xbf, tierC, n_edges);
        csr_blocksum<<<nscan, 256, 0, stream>>>(counts, bsum, n_nodes);
        csr_scan_bsum<<<1, 256, 0, stream>>>(bsum, nscan);
        csr_scan_final<<<nscan, 256, 0, stream>>>(counts, bsum, offsets, cursor, n_nodes);

        const int n_windows = (n_nodes + (1 << WIN_SHIFT) - 1) >> WIN_SHIFT;  // 7
        csr_place_win<<<dim3(1024, n_windows), 256, 0, stream>>>(
            eidx, nid, use_nid, cursor, elist, n_edges);

        if (tierC) {
            csr_gather_bf16<<<(n_nodes * 64 + 255) / 256, 256, 0, stream>>>(
                xbf, offsets, elist, agg, n_nodes);
        } else {
            csr_gather4<<<(n_nodes * 64 + 255) / 256, 256, 0, stream>>>(
                x_edge, offsets, elist, agg, n_nodes);
        }
    } else {
        hipMemsetAsync(agg, 0, (size_t)n_nodes * D * sizeof(float), stream);
        long long threads = (long long)n_edges * 64;
        nb_scatter<<<(int)((threads + 255) / 256), 256, 0, stream>>>(
            x_edge, eidx, agg, n_edges);
    }

    nb_mlp<<<256, MLPB, 0, stream>>>(x_node, agg, W1, b1, W2, b2, out, n_nodes);
}

// Round 6
// 203.600 us; speedup vs baseline: 1.6031x; 1.6031x over previous
//
#include <hip/hip_runtime.h>

#define D 64          // node/edge feature dim
#define HID 128       // hidden dim
#define MLPB 1024     // MLP block size (16 waves)
#define WPB 16        // waves per MLP block
#define NB 8          // nodes per wave-batch
#define CAP 96        // elist slots per node (mean degree 32; Poisson tail ~0)
#define WIN_SHIFT 12  // 4096 nodes per place-window -> ~1.5MB elist window

typedef unsigned short ush;

// bf16 round-to-nearest-even (finite normals)
__device__ __forceinline__ ush f2bf(float f)
{
    unsigned u = __float_as_uint(f);
    return (ush)((u + 0x7FFF + ((u >> 16) & 1)) >> 16);
}
__device__ __forceinline__ float bf_lo(unsigned p) { return __uint_as_float(p << 16); }
__device__ __forceinline__ float bf_hi(unsigned p) { return __uint_as_float(p & 0xFFFF0000u); }

// ---------------------------------------------------------------------------
// Index dtype: reference says int64, harness may deliver int32. Probe high
// words of the first 64 pairs: int64 -> all zero (ids < 50000); int32 ->
// random node ids, P(all zero) ~ (2e-5)^64 ~ 0. Deterministic.
// ---------------------------------------------------------------------------
__device__ __forceinline__ bool detect_i64(const int* __restrict__ eidx, int lane)
{
    int probe = eidx[2 * lane + 1];
    return (__ballot(probe == 0) == ~0ULL);
}

// ---------------------------------------------------------------------------
// Windowed fixed-capacity place. Entry t in [0,2E): t<E -> src of edge t,
// else dst of edge t-E. blockIdx.y = node window; only in-window entries are
// committed this pass, so the window's elist range (~1.5MB) and counts stay
// cache-resident and a node's consecutive slots coalesce on few lines.
// Overflow (c >= CAP) goes to a list handled by a cleanup kernel.
// ---------------------------------------------------------------------------
__global__ __launch_bounds__(256)
void p1_place(const int* __restrict__ eidx, int* __restrict__ counts,
              int* __restrict__ elist, int* __restrict__ ovf_cnt,
              int2* __restrict__ ovf, int n_edges, int n_nodes)
{
    const int lo = blockIdx.y << WIN_SHIFT;
    const int hi = lo + (1 << WIN_SHIFT);
    const int E2 = 2 * n_edges;
    const bool is64 = detect_i64(eidx, threadIdx.x & 63);
    const int stride = gridDim.x * 256;
    for (int t = blockIdx.x * 256 + threadIdx.x; t < E2; t += stride) {
        int idx = is64 ? eidx[2 * (size_t)t] : eidx[t];
        if (idx >= lo && idx < hi) {
            int eid = (t < n_edges) ? t : t - n_edges;
            int c = atomicAdd(&counts[idx], 1);
            if (c < CAP) elist[(size_t)idx * CAP + c] = eid;
            else {
                int p = atomicAdd(ovf_cnt, 1);
                ovf[p] = make_int2(idx, eid);
            }
        }
    }
}

// ---------------------------------------------------------------------------
// Gather: agg[n] = sum over incident edges of x_edge[e]. One wave per node.
// 16 lanes x float4 cover one 256B row; 4 row slots (lane>>4), 4x unrolled
// -> 16 edges in flight. No LDS, low VGPR -> full occupancy.
// ---------------------------------------------------------------------------
__global__ __launch_bounds__(256)
void p2_gather(const float* __restrict__ x_edge, const int* __restrict__ counts,
               const int* __restrict__ elist, float* __restrict__ agg, int n_nodes)
{
    const int w = (blockIdx.x * 256 + threadIdx.x) >> 6;
    if (w >= n_nodes) return;
    const int lane = threadIdx.x & 63;
    const int sub = lane >> 4;       // row slot 0..3
    const int q   = lane & 15;       // float4 index within row
    const float4* __restrict__ xe4 = (const float4*)x_edge;

    int cnt = counts[w]; if (cnt > CAP) cnt = CAP;
    const int beg = w * CAP, end = beg + cnt;
    float4 acc = make_float4(0.f, 0.f, 0.f, 0.f);

    int i = beg + sub;
    for (; i + 12 < end; i += 16) {
        int e0 = elist[i];
        int e1 = elist[i + 4];
        int e2 = elist[i + 8];
        int e3 = elist[i + 12];
        float4 v0 = xe4[(size_t)e0 * 16 + q];
        float4 v1 = xe4[(size_t)e1 * 16 + q];
        float4 v2 = xe4[(size_t)e2 * 16 + q];
        float4 v3 = xe4[(size_t)e3 * 16 + q];
        acc.x += (v0.x + v1.x) + (v2.x + v3.x);
        acc.y += (v0.y + v1.y) + (v2.y + v3.y);
        acc.z += (v0.z + v1.z) + (v2.z + v3.z);
        acc.w += (v0.w + v1.w) + (v2.w + v3.w);
    }
    for (; i < end; i += 4) {
        float4 v = xe4[(size_t)elist[i] * 16 + q];
        acc.x += v.x; acc.y += v.y; acc.z += v.z; acc.w += v.w;
    }

    #pragma unroll
    for (int m = 16; m < 64; m <<= 1) {
        acc.x += __shfl_xor(acc.x, m);
        acc.y += __shfl_xor(acc.y, m);
        acc.z += __shfl_xor(acc.z, m);
        acc.w += __shfl_xor(acc.w, m);
    }
    if (sub == 0)
        ((float4*)agg)[(size_t)w * 16 + q] = acc;
}

// ---------------------------------------------------------------------------
// Overflow cleanup: usually 0 entries. One wave per entry, atomic add of the
// edge row into agg. Runs after p2_gather (which overwrites agg rows).
// ---------------------------------------------------------------------------
__global__ __launch_bounds__(256)
void p3_ovf(const float* __restrict__ x_edge, const int* __restrict__ ovf_cnt,
            const int2* __restrict__ ovf, float* __restrict__ agg)
{
    const int n = *ovf_cnt;
    const int lane = threadIdx.x & 63;
    const int wv = (blockIdx.x * 256 + threadIdx.x) >> 6;
    const int nw = gridDim.x * 4;
    for (int i = wv; i < n; i += nw) {
        int2 p = ovf[i];
        float v = x_edge[(size_t)p.y * D + lane];
        unsafeAtomicAdd(&agg[(size_t)p.x * D + lane], v);
    }
}

// ---------- fallback atomic scatter (tiny ws) ------------------------------
__global__ __launch_bounds__(256)
void nb_scatter(const float* __restrict__ x_edge, const int* __restrict__ eidx,
                float* __restrict__ agg, int n_edges)
{
    long long t = (long long)blockIdx.x * 256 + threadIdx.x;
    int e = (int)(t >> 6);
    if (e >= n_edges) return;
    int d = (int)(t & 63);
    bool is64 = detect_i64(eidx, threadIdx.x & 63);
    int s, dd;
    if (is64) {
        s  = eidx[2 * (size_t)e];
        dd = eidx[2 * ((size_t)n_edges + (size_t)e)];
    } else {
        s  = eidx[e];
        dd = eidx[n_edges + e];
    }
    float v = x_edge[(size_t)e * D + d];
    unsafeAtomicAdd(&agg[(size_t)s * D + d], v);
    unsafeAtomicAdd(&agg[(size_t)dd * D + d], v);
}

// ---------------------------------------------------------------------------
// MLP: out[n] = relu(concat(x_node[n], agg[n]) @ W1 + b1) @ W2 + b2
// NB=8 nodes per wave-batch. W1 staged as float2{W1[k][j],W1[k][j+64]} (one
// b64 feeds 16 FMAs); W2 staged bf16-packed (one b32 feeds 32 FMAs). s_buf
// holds inputs then hidden (overlaid). LDS ~145KB -> 1 block/CU, 16 waves.
// agg read from d_out, out written in place (row n touched only by its wave).
// ---------------------------------------------------------------------------
__global__ __launch_bounds__(MLPB, 1)
void p4_mlp(const float* __restrict__ x_node, const float* __restrict__ agg,
            const float* __restrict__ W1, const float* __restrict__ b1,
            const float* __restrict__ W2, const float* __restrict__ b2,
            float* __restrict__ out, int n_nodes)
{
    __shared__ float2   sW1p[HID * 64];        // 64 KB
    __shared__ unsigned sW2p[64 * 64];         // 16 KB
    __shared__ float    sb1[HID];
    __shared__ float    sb2[D];
    __shared__ float4   s_buf[WPB][128][2];    // 64 KB

    {
        for (int t = threadIdx.x; t < HID * 64; t += MLPB) {
            int k = t >> 6, j = t & 63;
            sW1p[t] = make_float2(W1[k * HID + j], W1[k * HID + 64 + j]);
        }
        for (int t = threadIdx.x; t < 64 * 64; t += MLPB) {
            int q = t >> 6, j = t & 63;
            unsigned lo = f2bf(W2[(2 * q) * D + j]);
            unsigned hi = f2bf(W2[(2 * q + 1) * D + j]);
            sW2p[t] = lo | (hi << 16);
        }
        if (threadIdx.x < 128) sb1[threadIdx.x] = b1[threadIdx.x];
        else if (threadIdx.x < 192) sb2[threadIdx.x - 128] = b2[threadIdx.x - 128];
    }
    __syncthreads();

    const int wave = threadIdx.x >> 6;
    const int lane = threadIdx.x & 63;
    const int group = blockIdx.x * WPB + wave;
    const int ngroups = gridDim.x * WPB;
    const int nbatches = (n_nodes + NB - 1) / NB;

    const float bh0 = sb1[lane], bh1 = sb1[64 + lane];
    const float bo  = sb2[lane];

    for (int g = group; g < nbatches; g += ngroups) {
        const int n0 = g * NB;

        float vx[NB], va[NB];
        #pragma unroll
        for (int b = 0; b < NB; ++b) {
            const int n = n0 + b;
            const bool ok = (n < n_nodes);
            vx[b] = ok ? x_node[(size_t)n * D + lane] : 0.f;
            va[b] = ok ? agg[(size_t)n * D + lane] : 0.f;
        }
        s_buf[wave][lane][0]      = make_float4(vx[0], vx[1], vx[2], vx[3]);
        s_buf[wave][lane][1]      = make_float4(vx[4], vx[5], vx[6], vx[7]);
        s_buf[wave][64 + lane][0] = make_float4(va[0], va[1], va[2], va[3]);
        s_buf[wave][64 + lane][1] = make_float4(va[4], va[5], va[6], va[7]);
        __builtin_amdgcn_wave_barrier();

        float a0[NB], a1[NB];
        #pragma unroll
        for (int b = 0; b < NB; ++b) { a0[b] = bh0; a1[b] = bh1; }

        #pragma unroll 2
        for (int k = 0; k < 128; ++k) {
            const float4 A0 = s_buf[wave][k][0];
            const float4 A1 = s_buf[wave][k][1];
            const float2 w  = sW1p[k * 64 + lane];
            a0[0] = fmaf(A0.x, w.x, a0[0]); a1[0] = fmaf(A0.x, w.y, a1[0]);
            a0[1] = fmaf(A0.y, w.x, a0[1]); a1[1] = fmaf(A0.y, w.y, a1[1]);
            a0[2] = fmaf(A0.z, w.x, a0[2]); a1[2] = fmaf(A0.z, w.y, a1[2]);
            a0[3] = fmaf(A0.w, w.x, a0[3]); a1[3] = fmaf(A0.w, w.y, a1[3]);
            a0[4] = fmaf(A1.x, w.x, a0[4]); a1[4] = fmaf(A1.x, w.y, a1[4]);
            a0[5] = fmaf(A1.y, w.x, a0[5]); a1[5] = fmaf(A1.y, w.y, a1[5]);
            a0[6] = fmaf(A1.z, w.x, a0[6]); a1[6] = fmaf(A1.z, w.y, a1[6]);
            a0[7] = fmaf(A1.w, w.x, a0[7]); a1[7] = fmaf(A1.w, w.y, a1[7]);
        }
        __builtin_amdgcn_wave_barrier();
        s_buf[wave][lane][0] = make_float4(fmaxf(a0[0], 0.f), fmaxf(a0[1], 0.f),
                                           fmaxf(a0[2], 0.f), fmaxf(a0[3], 0.f));
        s_buf[wave][lane][1] = make_float4(fmaxf(a0[4], 0.f), fmaxf(a0[5], 0.f),
                                           fmaxf(a0[6], 0.f), fmaxf(a0[7], 0.f));
        s_buf[wave][64 + lane][0] = make_float4(fmaxf(a1[0], 0.f), fmaxf(a1[1], 0.f),
                                                fmaxf(a1[2], 0.f), fmaxf(a1[3], 0.f));
        s_buf[wave][64 + lane][1] = make_float4(fmaxf(a1[4], 0.f), fmaxf(a1[5], 0.f),
                                                fmaxf(a1[6], 0.f), fmaxf(a1[7], 0.f));
        __builtin_amdgcn_wave_barrier();

        float o[NB];
        #pragma unroll
        for (int b = 0; b < NB; ++b) o[b] = bo;
        #pragma unroll 2
        for (int q2 = 0; q2 < 64; ++q2) {
            const unsigned wp = sW2p[q2 * 64 + lane];
            const float w0 = bf_lo(wp), w1 = bf_hi(wp);
            const float4 H0a = s_buf[wave][2 * q2][0];
            const float4 H0b = s_buf[wave][2 * q2][1];
            const float4 H1a = s_buf[wave][2 * q2 + 1][0];
            const float4 H1b = s_buf[wave][2 * q2 + 1][1];
            o[0] = fmaf(H0a.x, w0, o[0]); o[0] = fmaf(H1a.x, w1, o[0]);
            o[1] = fmaf(H0a.y, w0, o[1]); o[1] = fmaf(H1a.y, w1, o[1]);
            o[2] = fmaf(H0a.z, w0, o[2]); o[2] = fmaf(H1a.z, w1, o[2]);
            o[3] = fmaf(H0a.w, w0, o[3]); o[3] = fmaf(H1a.w, w1, o[3]);
            o[4] = fmaf(H0b.x, w0, o[4]); o[4] = fmaf(H1b.x, w1, o[4]);
            o[5] = fmaf(H0b.y, w0, o[5]); o[5] = fmaf(H1b.y, w1, o[5]);
            o[6] = fmaf(H0b.z, w0, o[6]); o[6] = fmaf(H1b.z, w1, o[6]);
            o[7] = fmaf(H0b.w, w0, o[7]); o[7] = fmaf(H1b.w, w1, o[7]);
        }
        #pragma unroll
        for (int b = 0; b < NB; ++b) {
            const int n = n0 + b;
            if (n < n_nodes) out[(size_t)n * D + lane] = o[b];
        }
    }
}

// ---------------------------------------------------------------------------
extern "C" void kernel_launch(void* const* d_in, const int* in_sizes, int n_in,
                              void* d_out, int out_size, void* d_ws, size_t ws_size,
                              hipStream_t stream)
{
    const float* x_node = (const float*)d_in[0];
    const float* x_edge = (const float*)d_in[1];
    const int*   eidx   = (const int*)d_in[2];
    const float* W1     = (const float*)d_in[3];
    const float* b1     = (const float*)d_in[4];
    const float* W2     = (const float*)d_in[5];
    const float* b2     = (const float*)d_in[6];
    float* out = (float*)d_out;

    const int n_nodes = in_sizes[0] / D;     // 50000
    const int n_edges = in_sizes[2] / 2;     // 800000
    const int E2 = 2 * n_edges;

    float* agg = out;   // agg lives in d_out; MLP rewrites rows in place

    // ws layout (ints): counts[N] | ovf_cnt[1] | pad | ovf[2E int2] | elist[N*CAP]
    const size_t w_counts = (size_t)n_nodes;
    const size_t w_ovfc   = w_counts + 1;
    const size_t w_ovf    = (w_ovfc + 1 + 1) & ~(size_t)1;       // 8B align
    const size_t w_elist  = w_ovf + (size_t)E2 * 2;
    const size_t w_total  = w_elist + (size_t)n_nodes * CAP;
    const size_t need     = w_total * 4;

    if (ws_size >= need) {
        int*  counts  = (int*)d_ws;
        int*  ovf_cnt = (int*)d_ws + w_ovfc;
        int2* ovf     = (int2*)((int*)d_ws + w_ovf);
        int*  elist   = (int*)d_ws + w_elist;

        // zero counts + ovf_cnt (contiguous region)
        hipMemsetAsync(counts, 0, ((size_t)n_nodes + 2) * 4, stream);

        const int n_windows = (n_nodes + (1 << WIN_SHIFT) - 1) >> WIN_SHIFT;  // 13
        p1_place<<<dim3(512, n_windows), 256, 0, stream>>>(
            eidx, counts, elist, ovf_cnt, ovf, n_edges, n_nodes);

        p2_gather<<<(n_nodes * 64 + 255) / 256, 256, 0, stream>>>(
            x_edge, counts, elist, agg, n_nodes);

        p3_ovf<<<64, 256, 0, stream>>>(x_edge, ovf_cnt, ovf, agg);
    } else {
        hipMemsetAsync(agg, 0, (size_t)n_nodes * D * sizeof(float), stream);
        long long threads = (long long)n_edges * 64;
        nb_scatter<<<(int)((threads + 255) / 256), 256, 0, stream>>>(
            x_edge, eidx, agg, n_edges);
    }

    p4_mlp<<<196, MLPB, 0, stream>>>(x_node, agg, W1, b1, W2, b2, out, n_nodes);
}